// Round 16
// baseline (86.277 us; speedup 1.0000x reference)
//
#include <hip/hip_runtime.h>
#include <hip/hip_fp16.h>

#define BATCH 32
#define TLEN  4096
#define CH    128      // C == F == 128
#define KW    3
#define DIL   8

#define BM    128                // output rows per block
#define HR    (BM + 2 * DIL)     // 144  h rows
#define WROWS (BM + 4 * DIL)     // 160  x rows

typedef _Float16 f16x8 __attribute__((ext_vector_type(8)));
typedef float    f32x4 __attribute__((ext_vector_type(4)));

// XOR swizzle on the f16-element index within a [row][128] linear tile:
// toggles bits 3-5 (16B units) by row&7. Involution; keeps 8-aligned
// indices 8-aligned (no carries). Readers/writers use SWZ; the DMA stage
// pre-swizzles the per-lane GLOBAL source so LDS stays linear (m173/r21).
#define SWZ(row, e) ((row) * CH + ((e) ^ (((row) & 7) << 3)))

// ---------------------------------------------------------------------------
// Prep: Wt[j][f][c] = (f16) W[c][j][f]   for both layers' kernels.
// ---------------------------------------------------------------------------
__global__ void prep_weights_kernel(const float* __restrict__ W1,
                                    const float* __restrict__ W2,
                                    _Float16* __restrict__ Wt1,
                                    _Float16* __restrict__ Wt2) {
    const int total = KW * CH * CH;
    int idx = blockIdx.x * 256 + threadIdx.x;
    if (idx >= 2 * total) return;
    const float* W  = (idx < total) ? W1 : W2;
    _Float16*    Wt = (idx < total) ? Wt1 : Wt2;
    int r = idx % total;
    int j = r / (CH * CH);
    int f = (r / CH) % CH;
    int c = r % CH;
    Wt[j * CH * CH + f * CH + c] = (_Float16)W[c * (KW * CH) + j * CH + f];
}

// ---------------------------------------------------------------------------
// Pre-pass: xh = (f16) x. BW-bound (~96MB): enables global_load_lds staging
// (DMA can't convert f32->f16) and halves x bytes in the fused kernel.
// 2048 blk x 256 thr x 4 iters x 8 elems = 16,777,216 = B*T*C exactly.
// ---------------------------------------------------------------------------
__global__ __launch_bounds__(256)
void x_to_f16_kernel(const float* __restrict__ x, _Float16* __restrict__ xh) {
    const size_t stride = (size_t)2048 * 256;
    const size_t i0 = (size_t)blockIdx.x * 256 + threadIdx.x;
#pragma unroll
    for (int k = 0; k < 4; ++k) {
        const size_t idx = (i0 + (size_t)k * stride) * 8;
        f32x4 v0 = *(const f32x4*)(x + idx);
        f32x4 v1 = *(const f32x4*)(x + idx + 4);
        f16x8 o;
        o[0] = (_Float16)v0[0]; o[1] = (_Float16)v0[1];
        o[2] = (_Float16)v0[2]; o[3] = (_Float16)v0[3];
        o[4] = (_Float16)v1[0]; o[5] = (_Float16)v1[1];
        o[6] = (_Float16)v1[2]; o[7] = (_Float16)v1[3];
        *(f16x8*)&xh[idx] = o;
    }
}

// ---------------------------------------------------------------------------
// Fused TemporalDeConvBlock — DMA-staged build (r14 base otherwise).
// Stage: 10 global_load_lds_dwordx4 per wave (wave-uniform LDS dest, lane
// strided 16B; per-lane global src pre-swizzled). One vmcnt drain at the
// __syncthreads -> the whole stage VALU/latency chain from r2-r15 is gone.
// LDS: linear xs[160*128] (40KB) + hs[144*128] (36KB) = 76KB -> 2 blk/CU.
// All LDS reads + VALU writes use SWZ (T2): without it, stride-256B b128
// reads are 16-way conflicts. 256 thr = 4 waves; wave w cols [32w,32w+32)
// as two 16-col subtiles; reg-resident weights; residual from xs (f16);
// XCD-aware bijective swizzle (grid 1024 = 8*128).
// LESSONS: caps below live-set spill (r3/r5); 512-thr pinned to 64 VGPR
// (r4/r6/r7); occupancy/barriers/conflicts/instr-count/reg-staging all
// proven non-binding (r8-r15). WRITE_SIZE ~65MB = no-spill invariant.
// ---------------------------------------------------------------------------
__global__ __launch_bounds__(256)
void fused_deconv_kernel(const _Float16* __restrict__ xh,
                         const _Float16* __restrict__ Wt1,
                         const float* __restrict__ bias1,
                         const _Float16* __restrict__ Wt2,
                         const float* __restrict__ bias2,
                         float* __restrict__ out)
{
    __shared__ __align__(16) _Float16 xs[WROWS * CH];   // 40960 B, linear
    __shared__ __align__(16) _Float16 hs[HR * CH];      // 36864 B, linear

    const int tid  = threadIdx.x;
    const int lane = tid & 63;
    const int wid  = tid >> 6;         // 0..3
    const int l15  = lane & 15;
    const int kg   = lane >> 4;        // 0..3
    const int kg8  = kg << 3;
    const int nc   = wid << 5;         // wave column base: 0,32,64,96

    // XCD-aware bijective swizzle: grid = 1024 = 8 XCDs x 128 chunks.
    const int bt0 = blockIdx.x;
    const int bt  = (bt0 & 7) * 128 + (bt0 >> 3);

    const int b  = bt >> 5;            // 32 tiles per batch
    const int t0 = (bt & 31) << 7;

    // ---- prefetch GEMM1 weight fragments (24 x 16B = 96 VGPRs); in flight
    // under the DMA staging below.
    f16x8 w1[12][2];
#pragma unroll
    for (int ks = 0; ks < 12; ++ks) {
        const int j  = ks >> 2;
        const int c0 = (ks & 3) << 5;
        const _Float16* wb = Wt1 + (size_t)j * (CH * CH) + c0 + kg8;
        w1[ks][0] = *(const f16x8*)(wb + (nc + l15) * CH);
        w1[ks][1] = *(const f16x8*)(wb + (nc + 16 + l15) * CH);
    }

    // ---- stage x window via global_load_lds (16B/lane, 1KB = 4 rows per
    // wave-op). Wave w owns rows [40w, 40w+40): 10 DMA ops. Source address
    // carries the inverse swizzle; LDS dest is linear (m104/m173).
    // Group OOB check is uniform per op: TLEN-t0 is a multiple of 4, so a
    // 4-row group is never split by the boundary (last tile: rows >=128 OOB).
    {
        const int rbase = wid * 40;
#pragma unroll
        for (int k = 0; k < 10; ++k) {
            const int r0  = rbase + k * 4;
            _Float16* dst = &xs[r0 * CH];
            const int row = r0 + (lane >> 4);
            if (t0 + r0 + 3 < TLEN) {
                const _Float16* src = xh + ((size_t)b * TLEN + (t0 + row)) * CH
                                      + ((l15 ^ (row & 7)) << 3);
                __builtin_amdgcn_global_load_lds(
                    (const __attribute__((address_space(1))) void*)src,
                    (__attribute__((address_space(3))) void*)dst,
                    16, 0, 0);
            } else {
                f16x8 z = {};
                *(f16x8*)(dst + lane * 8) = z;
            }
        }
    }

    const float bv1_0 = 128.0f * bias1[nc + l15];
    const float bv1_1 = 128.0f * bias1[nc + 16 + l15];
    const float bv2_0 = 128.0f * bias2[nc + l15];
    const float bv2_1 = 128.0f * bias2[nc + 16 + l15];

    __syncthreads();   // barrier 1: vmcnt drain completes the DMA; xs live

    // ---- GEMM1: h rows 0..143, cols [nc,nc+32) — 216 MFMA / 108 ds_read
    f32x4 acc1[9][2];
#pragma unroll
    for (int m = 0; m < 9; ++m) {
        acc1[m][0] = (f32x4){0.f, 0.f, 0.f, 0.f};
        acc1[m][1] = (f32x4){0.f, 0.f, 0.f, 0.f};
    }
#pragma unroll
    for (int ks = 0; ks < 12; ++ks) {
        const int j     = ks >> 2;
        const int c0    = (ks & 3) << 5;
        const int shift = (2 - j) * DIL;
#pragma unroll
        for (int m = 0; m < 9; ++m) {
            const int row = m * 16 + shift + l15;
            f16x8 af = *(const f16x8*)&xs[SWZ(row, c0 + kg8)];
            acc1[m][0] = __builtin_amdgcn_mfma_f32_16x16x32_f16(af, w1[ks][0], acc1[m][0], 0, 0, 0);
            acc1[m][1] = __builtin_amdgcn_mfma_f32_16x16x32_f16(af, w1[ks][1], acc1[m][1], 0, 0, 0);
        }
    }

    // ---- prefetch GEMM2 weights (w1 dead, regs recycle)
    f16x8 w2[12][2];
#pragma unroll
    for (int ks = 0; ks < 12; ++ks) {
        const int j  = ks >> 2;
        const int c0 = (ks & 3) << 5;
        const _Float16* wb = Wt2 + (size_t)j * (CH * CH) + c0 + kg8;
        w2[ks][0] = *(const f16x8*)(wb + (nc + l15) * CH);
        w2[ks][1] = *(const f16x8*)(wb + (nc + 16 + l15) * CH);
    }

    // ---- store h rows 0..143 into hs (relu + bias), swizzled
#pragma unroll
    for (int m = 0; m < 9; ++m) {
#pragma unroll
        for (int nn = 0; nn < 2; ++nn) {
            const float bv = nn ? bv1_1 : bv1_0;
            const int f = nc + nn * 16 + l15;
#pragma unroll
            for (int i = 0; i < 4; ++i) {
                const int r = m * 16 + kg * 4 + i;
                const int u = t0 + r;
                const int nv = 1 + (u < TLEN - DIL) + (u < TLEN - 2 * DIL);
                float v = acc1[m][nn][i] + (float)nv * bv;
                v = fmaxf(v, 0.0f);
                hs[SWZ(r, f)] = (u < TLEN) ? (_Float16)v : (_Float16)0.0f;
            }
        }
    }
    __syncthreads();   // barrier 2: hs published

    // ---- GEMM2: out rows 0..127, cols [nc,nc+32) — 192 MFMA / 96 ds_read
    f32x4 acc2[8][2];
#pragma unroll
    for (int m = 0; m < 8; ++m) {
        acc2[m][0] = (f32x4){0.f, 0.f, 0.f, 0.f};
        acc2[m][1] = (f32x4){0.f, 0.f, 0.f, 0.f};
    }
#pragma unroll
    for (int ks = 0; ks < 12; ++ks) {
        const int j     = ks >> 2;
        const int c0    = (ks & 3) << 5;
        const int shift = (2 - j) * DIL;
#pragma unroll
        for (int m = 0; m < 8; ++m) {
            const int row = m * 16 + shift + l15;
            f16x8 af = *(const f16x8*)&hs[SWZ(row, c0 + kg8)];
            acc2[m][0] = __builtin_amdgcn_mfma_f32_16x16x32_f16(af, w2[ks][0], acc2[m][0], 0, 0, 0);
            acc2[m][1] = __builtin_amdgcn_mfma_f32_16x16x32_f16(af, w2[ks][1], acc2[m][1], 0, 0, 0);
        }
    }

    // ---- epilogue: bias2 + relu, + residual (f16 from xs, swizzled read),
    // relu, store f32
#pragma unroll
    for (int m = 0; m < 8; ++m) {
#pragma unroll
        for (int nn = 0; nn < 2; ++nn) {
            const float bv = nn ? bv2_1 : bv2_0;
            const int f = nc + nn * 16 + l15;
#pragma unroll
            for (int i = 0; i < 4; ++i) {
                const int r = m * 16 + kg * 4 + i;
                const int t = t0 + r;
                const int nv = 1 + (t < TLEN - DIL) + (t < TLEN - 2 * DIL);
                float v = acc2[m][nn][i] + (float)nv * bv;
                v = fmaxf(v, 0.0f);
                v = fmaxf(v + (float)xs[SWZ(r, f)], 0.0f);
                out[((size_t)b * TLEN + t) * CH + f] = v;
            }
        }
    }
}

// ---------------------------------------------------------------------------
extern "C" void kernel_launch(void* const* d_in, const int* in_sizes, int n_in,
                              void* d_out, int out_size, void* d_ws, size_t ws_size,
                              hipStream_t stream) {
    const float* x  = (const float*)d_in[0];
    const float* W1 = (const float*)d_in[1];
    const float* b1 = (const float*)d_in[2];
    const float* W2 = (const float*)d_in[3];
    const float* b2 = (const float*)d_in[4];
    float* out = (float*)d_out;

    // ws layout: xh (B*T*C f16, 32MB) | Wt1 | Wt2
    _Float16* xh  = (_Float16*)d_ws;
    _Float16* Wt1 = xh + (size_t)BATCH * TLEN * CH;
    _Float16* Wt2 = Wt1 + KW * CH * CH;

    prep_weights_kernel<<<(2 * KW * CH * CH + 255) / 256, 256, 0, stream>>>(W1, W2, Wt1, Wt2);
    x_to_f16_kernel<<<2048, 256, 0, stream>>>(x, xh);

    const int grid = BATCH * (TLEN / BM);   // 1024 blocks (= 8 XCDs x 128)
    fused_deconv_kernel<<<grid, 256, 0, stream>>>(xh, Wt1, b1, Wt2, b2, out);
}

// Round 17
// 69.341 us; speedup vs baseline: 1.2442x; 1.2442x over previous
//
#include <hip/hip_runtime.h>
#include <hip/hip_fp16.h>

#define BATCH 32
#define TLEN  4096
#define CH    128      // C == F == 128
#define KW    3
#define DIL   8

#define BM    128                // output rows per block
#define HR    (BM + 2 * DIL)     // 144  h rows needed
#define WROWS (BM + 4 * DIL)     // 160  x rows needed
#define LDSC  132                // 264B stride = 66 dwords ≡ 2 (mod 32): ~2-way
                                 // bank alias (free). 136 (≡4 mod 32) gave 8-way
                                 // conflicts (r6-r11). Keep stride ≢ 0/4 mod 32.

#define WFRAG (12 * 2 * 64 * 8)  // per-wave fragment block: 12288 f16 = 24KB
#define WTOT  (4 * WFRAG)        // per-layer: 49152 f16 = 96KB

typedef _Float16 f16x8 __attribute__((ext_vector_type(8)));
typedef float    f32x4 __attribute__((ext_vector_type(4)));

// ---------------------------------------------------------------------------
// Prep: FRAGMENT-ORDER weight layout.
//   Wf[wd][ks][nn][lane][e] = (f16) W[c][j][f]
//     j = ks>>2,  f = wd*32 + nn*16 + (lane&15),  c = (ks&3)*32 + (lane>>4)*8 + e
// One wave's (ks,nn) load = 64 lanes x 16B CONTIGUOUS (1KB, 16 cache lines).
// The old [f][c] layout made every weight load a 256B-stride gather: 64
// distinct cache lines per instruction x 48 instr/wave x 16 waves/CU ≈ 49K
// serialized L1 line-lookups per CU — the r8-r16 invariant stall.
// ---------------------------------------------------------------------------
__global__ void prep_weights_kernel(const float* __restrict__ W1,
                                    const float* __restrict__ W2,
                                    _Float16* __restrict__ Wf1,
                                    _Float16* __restrict__ Wf2) {
    int idx = blockIdx.x * 256 + threadIdx.x;
    if (idx >= 2 * WTOT) return;
    const float* W  = (idx < WTOT) ? W1 : W2;
    _Float16*    Wf = (idx < WTOT) ? Wf1 : Wf2;
    int r = idx % WTOT;
    const int e    = r & 7;
    const int lane = (r >> 3) & 63;
    const int nn   = (r >> 9) & 1;
    const int t    = r >> 10;          // 0..47 = wd*12 + ks
    const int ks   = t % 12;
    const int wd   = t / 12;
    const int j = ks >> 2;
    const int f = wd * 32 + nn * 16 + (lane & 15);
    const int c = (ks & 3) * 32 + (lane >> 4) * 8 + e;
    Wf[r] = (_Float16)W[c * (KW * CH) + j * CH + f];
}

// ---------------------------------------------------------------------------
// Fused TemporalDeConvBlock — r14 base (best: 66.6us) + fragment-order
// weight loads (1KB coalesced per instruction instead of 64-line gathers).
// 256 thr = 4 waves; wave w owns cols [32w,32w+32) as two 16-col subtiles
// (each A ds_read feeds 2 MFMA). BM=128 x-window staged once (f32->f16 in
// VALU); separate xs/hs buffers (2 barriers); residual from live xs window
// (f16); XCD-aware bijective block swizzle (grid 1024 = 8*128).
// LESSONS: caps below live-set spill (r3/r5); 512-thr blocks pinned to 64
// VGPR (r4/r6/r7); occupancy/barriers/conflicts/instr-count/staging-method/
// read-pipelining all proven non-binding (r8-r16). WRITE~65MB = no-spill.
// ---------------------------------------------------------------------------
__global__ __launch_bounds__(256)
void fused_deconv_kernel(const float* __restrict__ x,
                         const _Float16* __restrict__ Wf1,
                         const float* __restrict__ bias1,
                         const _Float16* __restrict__ Wf2,
                         const float* __restrict__ bias2,
                         float* __restrict__ out)
{
    __shared__ __align__(16) _Float16 xs[WROWS][LDSC];   // 160*264 = 42240 B
    __shared__ __align__(16) _Float16 hs[HR][LDSC];      // 144*264 = 38016 B

    const int tid  = threadIdx.x;
    const int lane = tid & 63;
    const int wid  = tid >> 6;         // 0..3
    const int l15  = lane & 15;
    const int kg   = lane >> 4;        // 0..3
    const int nc   = wid << 5;         // wave column base: 0,32,64,96

    // XCD-aware bijective swizzle: grid = 1024 = 8 XCDs x 128 chunks.
    const int bt0 = blockIdx.x;
    const int bt  = (bt0 & 7) * 128 + (bt0 >> 3);

    const int b  = bt >> 5;            // TLEN/BM = 32 tiles per batch
    const int t0 = (bt & 31) << 7;

    // per-wave fragment bases (contiguous 24KB each)
    const _Float16* wfb1 = Wf1 + wid * WFRAG + (lane << 3);
    const _Float16* wfb2 = Wf2 + wid * WFRAG + (lane << 3);

    // ---- prefetch GEMM1 weight fragments (24 x 1KB coalesced loads);
    // L2 latency overlaps the x staging below.
    f16x8 w1[12][2];
#pragma unroll
    for (int ks = 0; ks < 12; ++ks) {
        w1[ks][0] = *(const f16x8*)(wfb1 + ((ks * 2 + 0) << 9));
        w1[ks][1] = *(const f16x8*)(wfb1 + ((ks * 2 + 1) << 9));
    }

    // ---- stage x window (f32 -> f16), rows t0..t0+159, zero past TLEN.
#pragma unroll
    for (int p = 0; p < 10; ++p) {
        const int i   = tid + 256 * p;
        const int row = i >> 4;
        const int c8  = (i & 15) << 3;
        const int t   = t0 + row;
        f16x8 o;
        if (t < TLEN) {
            const float* xp = x + ((size_t)b * TLEN + t) * CH + c8;
            f32x4 v0 = *(const f32x4*)(xp + 0);
            f32x4 v1 = *(const f32x4*)(xp + 4);
            o[0] = (_Float16)v0[0]; o[1] = (_Float16)v0[1];
            o[2] = (_Float16)v0[2]; o[3] = (_Float16)v0[3];
            o[4] = (_Float16)v1[0]; o[5] = (_Float16)v1[1];
            o[6] = (_Float16)v1[2]; o[7] = (_Float16)v1[3];
        } else {
            o = (f16x8){};
        }
        *(f16x8*)&xs[row][c8] = o;
    }

    const float bv1_0 = 128.0f * bias1[nc + l15];
    const float bv1_1 = 128.0f * bias1[nc + 16 + l15];
    const float bv2_0 = 128.0f * bias2[nc + l15];
    const float bv2_1 = 128.0f * bias2[nc + 16 + l15];

    __syncthreads();   // barrier 1: xs published

    // ---- GEMM1: h rows 0..143, cols [nc,nc+32) — 216 MFMA / 108 ds_read
    f32x4 acc1[9][2];
#pragma unroll
    for (int m = 0; m < 9; ++m) {
        acc1[m][0] = (f32x4){0.f, 0.f, 0.f, 0.f};
        acc1[m][1] = (f32x4){0.f, 0.f, 0.f, 0.f};
    }
#pragma unroll
    for (int ks = 0; ks < 12; ++ks) {
        const int j     = ks >> 2;
        const int c0    = (ks & 3) << 5;
        const int shift = (2 - j) * DIL;
#pragma unroll
        for (int m = 0; m < 9; ++m) {
            f16x8 af = *(const f16x8*)&xs[m * 16 + shift + l15][c0 + kg * 8];
            acc1[m][0] = __builtin_amdgcn_mfma_f32_16x16x32_f16(af, w1[ks][0], acc1[m][0], 0, 0, 0);
            acc1[m][1] = __builtin_amdgcn_mfma_f32_16x16x32_f16(af, w1[ks][1], acc1[m][1], 0, 0, 0);
        }
    }

    // ---- prefetch GEMM2 weights (w1 dead, regs recycle); latency hides
    // under the h-store below. Coalesced 1KB loads.
    f16x8 w2[12][2];
#pragma unroll
    for (int ks = 0; ks < 12; ++ks) {
        w2[ks][0] = *(const f16x8*)(wfb2 + ((ks * 2 + 0) << 9));
        w2[ks][1] = *(const f16x8*)(wfb2 + ((ks * 2 + 1) << 9));
    }

    // ---- store h rows 0..143 into hs (relu + bias)
#pragma unroll
    for (int m = 0; m < 9; ++m) {
#pragma unroll
        for (int nn = 0; nn < 2; ++nn) {
            const float bv = nn ? bv1_1 : bv1_0;
            const int f = nc + nn * 16 + l15;
#pragma unroll
            for (int i = 0; i < 4; ++i) {
                const int r = m * 16 + kg * 4 + i;
                const int u = t0 + r;
                const int nv = 1 + (u < TLEN - DIL) + (u < TLEN - 2 * DIL);
                float v = acc1[m][nn][i] + (float)nv * bv;
                v = fmaxf(v, 0.0f);
                hs[r][f] = (u < TLEN) ? (_Float16)v : (_Float16)0.0f;
            }
        }
    }
    __syncthreads();   // barrier 2: hs published

    // ---- GEMM2: out rows 0..127, cols [nc,nc+32) — 192 MFMA / 96 ds_read
    f32x4 acc2[8][2];
#pragma unroll
    for (int m = 0; m < 8; ++m) {
        acc2[m][0] = (f32x4){0.f, 0.f, 0.f, 0.f};
        acc2[m][1] = (f32x4){0.f, 0.f, 0.f, 0.f};
    }
#pragma unroll
    for (int ks = 0; ks < 12; ++ks) {
        const int j     = ks >> 2;
        const int c0    = (ks & 3) << 5;
        const int shift = (2 - j) * DIL;
#pragma unroll
        for (int m = 0; m < 8; ++m) {
            f16x8 af = *(const f16x8*)&hs[m * 16 + shift + l15][c0 + kg * 8];
            acc2[m][0] = __builtin_amdgcn_mfma_f32_16x16x32_f16(af, w2[ks][0], acc2[m][0], 0, 0, 0);
            acc2[m][1] = __builtin_amdgcn_mfma_f32_16x16x32_f16(af, w2[ks][1], acc2[m][1], 0, 0, 0);
        }
    }

    // ---- epilogue: bias2 + relu, + residual (f16 from live xs window),
    // relu, store f32
#pragma unroll
    for (int m = 0; m < 8; ++m) {
#pragma unroll
        for (int nn = 0; nn < 2; ++nn) {
            const float bv = nn ? bv2_1 : bv2_0;
            const int f = nc + nn * 16 + l15;
#pragma unroll
            for (int i = 0; i < 4; ++i) {
                const int r = m * 16 + kg * 4 + i;
                const int t = t0 + r;
                const int nv = 1 + (t < TLEN - DIL) + (t < TLEN - 2 * DIL);
                float v = acc2[m][nn][i] + (float)nv * bv;
                v = fmaxf(v, 0.0f);
                v = fmaxf(v + (float)xs[r][f], 0.0f);
                out[((size_t)b * TLEN + t) * CH + f] = v;
            }
        }
    }
}

// ---------------------------------------------------------------------------
extern "C" void kernel_launch(void* const* d_in, const int* in_sizes, int n_in,
                              void* d_out, int out_size, void* d_ws, size_t ws_size,
                              hipStream_t stream) {
    const float* x  = (const float*)d_in[0];
    const float* W1 = (const float*)d_in[1];
    const float* b1 = (const float*)d_in[2];
    const float* W2 = (const float*)d_in[3];
    const float* b2 = (const float*)d_in[4];
    float* out = (float*)d_out;

    // ws layout: Wf1 (96KB) | Wf2 (96KB)
    _Float16* Wf1 = (_Float16*)d_ws;
    _Float16* Wf2 = Wf1 + WTOT;

    prep_weights_kernel<<<(2 * WTOT + 255) / 256, 256, 0, stream>>>(W1, W2, Wf1, Wf2);

    const int grid = BATCH * (TLEN / BM);   // 1024 blocks (= 8 XCDs x 128)
    fused_deconv_kernel<<<grid, 256, 0, stream>>>(x, Wf1, b1, Wf2, b2, out);
}